// Round 2
// baseline (1070.676 us; speedup 1.0000x reference)
//
#include <hip/hip_runtime.h>
#include <stdint.h>
#include <stddef.h>

// ---------- types ----------
typedef __attribute__((ext_vector_type(8))) short     bf16x8;
typedef __attribute__((ext_vector_type(4))) float     f32x4;
typedef __attribute__((ext_vector_type(4))) float     f32x4v;
typedef __attribute__((ext_vector_type(4))) int       i32x4;
typedef __attribute__((ext_vector_type(8))) unsigned short u16x8;
typedef __attribute__((ext_vector_type(4))) unsigned short u16x4;

__device__ __forceinline__ unsigned short f2bf(float f) {
    union { float f; unsigned u; } v; v.f = f;
    unsigned r = v.u + 0x7FFFu + ((v.u >> 16) & 1u);
    return (unsigned short)(r >> 16);
}

__device__ __forceinline__ void gload_lds16(const void* g, void* l) {
    __builtin_amdgcn_global_load_lds(
        (const __attribute__((address_space(1))) void*)(g),
        (__attribute__((address_space(3))) void*)(l), 16, 0, 0);
}

// ---------- convert kernels ----------
__global__ void cvt_x_kernel(const float* __restrict__ x, unsigned short* __restrict__ o, int n8) {
    int i = blockIdx.x * blockDim.x + threadIdx.x;
    int stride = gridDim.x * blockDim.x;
    for (; i < n8; i += stride) {
        f32x4v a = ((const f32x4v*)x)[2 * (size_t)i];
        f32x4v b = ((const f32x4v*)x)[2 * (size_t)i + 1];
        u16x8 r;
        r[0] = f2bf(a[0]); r[1] = f2bf(a[1]); r[2] = f2bf(a[2]); r[3] = f2bf(a[3]);
        r[4] = f2bf(b[0]); r[5] = f2bf(b[1]); r[6] = f2bf(b[2]); r[7] = f2bf(b[3]);
        ((u16x8*)o)[i] = r;
    }
}

__global__ void cvt_w_kernel(const int* __restrict__ w, unsigned short* __restrict__ o, int n8) {
    int i = blockIdx.x * blockDim.x + threadIdx.x;
    int stride = gridDim.x * blockDim.x;
    for (; i < n8; i += stride) {
        i32x4 a = ((const i32x4*)w)[2 * (size_t)i];
        i32x4 b = ((const i32x4*)w)[2 * (size_t)i + 1];
        u16x8 r;
        r[0] = f2bf((float)a[0]); r[1] = f2bf((float)a[1]);
        r[2] = f2bf((float)a[2]); r[3] = f2bf((float)a[3]);
        r[4] = f2bf((float)b[0]); r[5] = f2bf((float)b[1]);
        r[6] = f2bf((float)b[2]); r[7] = f2bf((float)b[3]);
        ((u16x8*)o)[i] = r;
    }
}

// =====================================================================
// 256x256 8-phase GEMM (T2 swizzle + T3/T4 counted vmcnt + T5 setprio)
// C[m][n] = (sum_k A[m][k]*W[n][k]) * scale + bias[n]; A,W bf16 K-contig.
// 512 thr = 8 waves (2M x 4N); wave tile 128x64; BK=64; 4 phases/K-tile.
// LDS: [2 buf][4 regions: A0,A1,B0,B1][16KB]. Stage: P1->B0(t+1),
// P2->B1(t+1), P3->A0(t+2), P4->A1(t+2); vmcnt(4) at each P4 only.
// Swizzle: byte col c2 ^= ((row&7)<<4); gload_lds writes linear LDS with
// pre-swizzled GLOBAL source; ds_read applies the same XOR (rule #21).
// =====================================================================
#define BM8 256
#define BN8 256
#define BK8 64

__global__ __launch_bounds__(512, 2) void gemm8p(
    const unsigned short* __restrict__ A,   // [M][K] bf16
    const unsigned short* __restrict__ Bw,  // [N][K] bf16
    const float* __restrict__ scale_p,
    const float* __restrict__ bias,
    float* __restrict__ C,
    int M, int N, int K)
{
    __shared__ __align__(16) char smem[131072];

    const int t    = threadIdx.x;
    const int lane = t & 63;
    const int w    = t >> 6;     // 0..7
    const int wm   = w >> 2;     // 0..1  (M half)
    const int wn   = w & 3;      // 0..3  (N quarter)

    int nwg = gridDim.x, bid = blockIdx.x;
    int swz = ((nwg & 7) == 0) ? ((bid & 7) * (nwg >> 3) + (bid >> 3)) : bid;
    const int ntn  = N / BN8;
    const int row0 = (swz / ntn) * BM8;
    const int col0 = (swz % ntn) * BN8;

    const int Kb = K * 2;
    const int NT = K / BK8;

    // staging geometry: load i covers rows i*64 + w*8 + (lane>>3), 16B at
    // swizzled source col; LDS dest linear (wave base + lane*16).
    const int srow = w * 8 + (lane >> 3);               // 0..63
    const int sc2  = ((lane & 7) ^ (lane >> 3)) * 16;   // pre-swizzled col bytes
    const int ldsLaneOff = w * 1024 + lane * 16;

    const char* Ab = (const char*)A + (size_t)row0 * Kb;
    const char* Bb = (const char*)Bw + (size_t)col0 * Kb;

    // frag-read geometry
    const int q    = lane >> 4;        // 0..3 k-chunk
    const int lr   = lane & 15;        // row within 16
    const int swzr = (lr & 7) << 4;    // read-side XOR

    f32x4 acc[8][4] = {};
    bf16x8 aF[4][2], aS[4][2], bF[2][2], bS[2][2];

#define STAGE(gb, half, tj, buf, region) do {                                        \
    const char* _g = (gb) + (size_t)((half) * 128 + srow) * Kb                        \
                     + (size_t)(tj) * (BK8 * 2) + sc2;                                \
    char* _l = &smem[(buf) * 65536 + (region) * 16384 + ldsLaneOff];                  \
    gload_lds16(_g, _l);                                                              \
    gload_lds16(_g + (size_t)64 * Kb, _l + 8192);                                     \
} while (0)

#define RDA(buf, mi, ks) \
    (*(const bf16x8*)&smem[(buf) * 65536 + wm * 16384 + ((mi) * 16 + lr) * 128 \
                           + ((((ks) << 6) | (q << 4)) ^ swzr)])
#define RDB(buf, nj, ks) \
    (*(const bf16x8*)&smem[(buf) * 65536 + (2 + (wn >> 1)) * 16384              \
                           + ((wn & 1) * 64 + (nj) * 16 + lr) * 128             \
                           + ((((ks) << 6) | (q << 4)) ^ swzr)])

#define MFMA_(a, b, c) (c) = __builtin_amdgcn_mfma_f32_16x16x32_bf16((a), (b), (c), 0, 0, 0)
#define BAR() __builtin_amdgcn_s_barrier()
#define LGKM0() do { asm volatile("s_waitcnt lgkmcnt(0)" ::: "memory"); \
                     __builtin_amdgcn_sched_barrier(0); } while (0)
#define VM4() asm volatile("s_waitcnt vmcnt(4)" ::: "memory")
#define VM0() asm volatile("s_waitcnt vmcnt(0)" ::: "memory")
#define VMNONE() do { } while (0)

#define TILE_STEP(tt, bb, stB, stA2, VMW) do {                                        \
    /* ---- phase 1: read A[m0-3]+B[n0-1]; stage B0(t+1); MFMA q(0-3,0-1) ---- */     \
    _Pragma("unroll") for (int mi = 0; mi < 4; ++mi) {                                \
        aF[mi][0] = RDA(bb, mi, 0); aF[mi][1] = RDA(bb, mi, 1); }                     \
    _Pragma("unroll") for (int nj = 0; nj < 2; ++nj) {                                \
        bF[nj][0] = RDB(bb, nj, 0); bF[nj][1] = RDB(bb, nj, 1); }                     \
    if (stB) STAGE(Bb, 0, (tt) + 1, (bb) ^ 1, 2);                                     \
    asm volatile("s_waitcnt lgkmcnt(8)" ::: "memory");                                \
    BAR(); LGKM0();                                                                   \
    __builtin_amdgcn_s_setprio(1);                                                    \
    _Pragma("unroll") for (int mi = 0; mi < 4; ++mi)                                  \
    _Pragma("unroll") for (int nj = 0; nj < 2; ++nj) {                                \
        MFMA_(aF[mi][0], bF[nj][0], acc[mi][nj]);                                     \
        MFMA_(aF[mi][1], bF[nj][1], acc[mi][nj]); }                                   \
    __builtin_amdgcn_s_setprio(0);                                                    \
    BAR();                                                                            \
    /* ---- phase 2: read A[m4-7]; stage B1(t+1); MFMA q(4-7,0-1) ---- */             \
    _Pragma("unroll") for (int mi = 0; mi < 4; ++mi) {                                \
        aS[mi][0] = RDA(bb, 4 + mi, 0); aS[mi][1] = RDA(bb, 4 + mi, 1); }             \
    if (stB) STAGE(Bb, 1, (tt) + 1, (bb) ^ 1, 3);                                     \
    BAR(); LGKM0();                                                                   \
    __builtin_amdgcn_s_setprio(1);                                                    \
    _Pragma("unroll") for (int mi = 0; mi < 4; ++mi)                                  \
    _Pragma("unroll") for (int nj = 0; nj < 2; ++nj) {                                \
        MFMA_(aS[mi][0], bF[nj][0], acc[4 + mi][nj]);                                 \
        MFMA_(aS[mi][1], bF[nj][1], acc[4 + mi][nj]); }                               \
    __builtin_amdgcn_s_setprio(0);                                                    \
    BAR();                                                                            \
    /* ---- phase 3: read B[n2-3]; stage A0(t+2); MFMA q(4-7,2-3) ---- */             \
    _Pragma("unroll") for (int nj = 0; nj < 2; ++nj) {                                \
        bS[nj][0] = RDB(bb, 2 + nj, 0); bS[nj][1] = RDB(bb, 2 + nj, 1); }             \
    if (stA2) STAGE(Ab, 0, (tt) + 2, (bb), 0);                                        \
    BAR(); LGKM0();                                                                   \
    __builtin_amdgcn_s_setprio(1);                                                    \
    _Pragma("unroll") for (int mi = 0; mi < 4; ++mi)                                  \
    _Pragma("unroll") for (int nj = 0; nj < 2; ++nj) {                                \
        MFMA_(aS[mi][0], bS[nj][0], acc[4 + mi][2 + nj]);                             \
        MFMA_(aS[mi][1], bS[nj][1], acc[4 + mi][2 + nj]); }                           \
    __builtin_amdgcn_s_setprio(0);                                                    \
    BAR();                                                                            \
    /* ---- phase 4: stage A1(t+2); MFMA q(0-3,2-3); tile-boundary vmcnt ---- */      \
    if (stA2) STAGE(Ab, 1, (tt) + 2, (bb), 1);                                        \
    BAR();                                                                            \
    __builtin_amdgcn_s_setprio(1);                                                    \
    _Pragma("unroll") for (int mi = 0; mi < 4; ++mi)                                  \
    _Pragma("unroll") for (int nj = 0; nj < 2; ++nj) {                                \
        MFMA_(aF[mi][0], bS[nj][0], acc[mi][2 + nj]);                                 \
        MFMA_(aF[mi][1], bS[nj][1], acc[mi][2 + nj]); }                               \
    __builtin_amdgcn_s_setprio(0);                                                    \
    VMW();                                                                            \
    BAR();                                                                            \
} while (0)

    // prologue: stage tile0 {A0,A1,B0,B1} + tile1 {A0,A1}; vmcnt(4) -> tile0 done
    STAGE(Ab, 0, 0, 0, 0); STAGE(Ab, 1, 0, 0, 1);
    STAGE(Bb, 0, 0, 0, 2); STAGE(Bb, 1, 0, 0, 3);
    STAGE(Ab, 0, 1, 1, 0); STAGE(Ab, 1, 1, 1, 1);
    VM4();
    BAR();

    for (int tt = 0; tt < NT - 2; tt += 2) {
        TILE_STEP(tt,     0, 1, 1, VM4);
        TILE_STEP(tt + 1, 1, 1, 1, VM4);
    }
    TILE_STEP(NT - 2, 0, 1, 0, VM0);     // stage B(NT-1) only; full drain
    TILE_STEP(NT - 1, 1, 0, 0, VMNONE);  // pure compute

    // ---- epilogue ----
    const float s = scale_p[0];
    float bv[4];
#pragma unroll
    for (int nj = 0; nj < 4; ++nj) bv[nj] = bias[col0 + wn * 64 + nj * 16 + lr];
#pragma unroll
    for (int mi = 0; mi < 8; ++mi) {
#pragma unroll
        for (int nj = 0; nj < 4; ++nj) {
            const int col = col0 + wn * 64 + nj * 16 + lr;
#pragma unroll
            for (int j = 0; j < 4; ++j) {
                const int row = row0 + wm * 128 + mi * 16 + q * 4 + j;
                C[(size_t)row * N + col] = acc[mi][nj][j] * s + bv[nj];
            }
        }
    }
#undef STAGE
#undef RDA
#undef RDB
#undef TILE_STEP
}

// ---------- fallback 128x128 (round-1, known-good) ----------
#define BM 128
#define BN 128
#define BK 64

__global__ __launch_bounds__(256, 2) void gemm_bt(
    const unsigned short* __restrict__ A,
    const unsigned short* __restrict__ Bw,
    const float* __restrict__ scale_p,
    const float* __restrict__ bias,
    float* __restrict__ C,
    int M, int N, int K)
{
    __shared__ unsigned short As[BM * BK];
    __shared__ unsigned short Bs[BN * BK];

    const int t = threadIdx.x, lane = t & 63, w = t >> 6;
    const int wm = w >> 1, wn = w & 1;
    int nwg = gridDim.x, bid = blockIdx.x;
    int swz = (nwg % 8 == 0) ? ((bid & 7) * (nwg >> 3) + (bid >> 3)) : bid;
    const int ntn = N / BN;
    const int row0 = (swz / ntn) * BM, col0 = (swz % ntn) * BN;
    const int sr = t >> 3, sc = (t & 7) * 8;
    f32x4 acc[4][4] = {};
    const size_t ldK = (size_t)K;
    const int lr = lane & 15, lkbase = (lane >> 4) * 8;

    for (int kt = 0; kt < K; kt += BK) {
#pragma unroll
        for (int i = 0; i < 4; ++i)
            gload_lds16(A + (size_t)(row0 + i * 32 + sr) * ldK + kt + sc, &As[(i * 256 + t) * 8]);
#pragma unroll
        for (int i = 0; i < 4; ++i)
            gload_lds16(Bw + (size_t)(col0 + i * 32 + sr) * ldK + kt + sc, &Bs[(i * 256 + t) * 8]);
        __syncthreads();
#pragma unroll
        for (int ks = 0; ks < 2; ++ks) {
            const int lk = lkbase + ks * 32;
            bf16x8 af[4], bfr[4];
#pragma unroll
            for (int m = 0; m < 4; ++m) af[m] = *(const bf16x8*)&As[(wm * 64 + m * 16 + lr) * BK + lk];
#pragma unroll
            for (int n = 0; n < 4; ++n) bfr[n] = *(const bf16x8*)&Bs[(wn * 64 + n * 16 + lr) * BK + lk];
#pragma unroll
            for (int m = 0; m < 4; ++m)
#pragma unroll
                for (int n = 0; n < 4; ++n)
                    acc[m][n] = __builtin_amdgcn_mfma_f32_16x16x32_bf16(af[m], bfr[n], acc[m][n], 0, 0, 0);
        }
        __syncthreads();
    }
    const float s = scale_p[0];
    const int lq4 = (lane >> 4) * 4;
#pragma unroll
    for (int m = 0; m < 4; ++m)
#pragma unroll
        for (int n = 0; n < 4; ++n) {
            const int col = col0 + wn * 64 + n * 16 + lr;
            const float bv = bias[col];
#pragma unroll
            for (int j = 0; j < 4; ++j) {
                const int row = row0 + wm * 64 + m * 16 + lq4 + j;
                C[(size_t)row * N + col] = acc[m][n][j] * s + bv;
            }
        }
}

// ---------- fallback: fused convert-in-staging GEMM (ws too small) ----------
__global__ __launch_bounds__(256, 2) void gemm_fused(
    const float* __restrict__ A,
    const int* __restrict__ Bw,
    const float* __restrict__ scale_p,
    const float* __restrict__ bias,
    float* __restrict__ C,
    int M, int N, int K)
{
    __shared__ unsigned short As[BM * BK];
    __shared__ unsigned short Bs[BN * BK];
    const int t = threadIdx.x, lane = t & 63, w = t >> 6;
    const int wm = w >> 1, wn = w & 1;
    int nwg = gridDim.x, bid = blockIdx.x;
    int swz = (nwg % 8 == 0) ? ((bid & 7) * (nwg >> 3) + (bid >> 3)) : bid;
    const int ntn = N / BN;
    const int row0 = (swz / ntn) * BM, col0 = (swz % ntn) * BN;
    f32x4 acc[4][4] = {};
    const int lr = lane & 15, lkbase = (lane >> 4) * 8;

    for (int kt = 0; kt < K; kt += BK) {
#pragma unroll
        for (int i = 0; i < 8; ++i) {
            const int r = i * 16 + (t >> 4), c = (t & 15) * 4;
            f32x4v v = *(const f32x4v*)&A[(size_t)(row0 + r) * K + kt + c];
            u16x4 o; o[0] = f2bf(v[0]); o[1] = f2bf(v[1]); o[2] = f2bf(v[2]); o[3] = f2bf(v[3]);
            *(u16x4*)&As[r * BK + c] = o;
        }
#pragma unroll
        for (int i = 0; i < 8; ++i) {
            const int r = i * 16 + (t >> 4), c = (t & 15) * 4;
            i32x4 v = *(const i32x4*)&Bw[(size_t)(col0 + r) * K + kt + c];
            u16x4 o; o[0] = f2bf((float)v[0]); o[1] = f2bf((float)v[1]);
                     o[2] = f2bf((float)v[2]); o[3] = f2bf((float)v[3]);
            *(u16x4*)&Bs[r * BK + c] = o;
        }
        __syncthreads();
#pragma unroll
        for (int ks = 0; ks < 2; ++ks) {
            const int lk = lkbase + ks * 32;
            bf16x8 af[4], bfr[4];
#pragma unroll
            for (int m = 0; m < 4; ++m) af[m] = *(const bf16x8*)&As[(wm * 64 + m * 16 + lr) * BK + lk];
#pragma unroll
            for (int n = 0; n < 4; ++n) bfr[n] = *(const bf16x8*)&Bs[(wn * 64 + n * 16 + lr) * BK + lk];
#pragma unroll
            for (int m = 0; m < 4; ++m)
#pragma unroll
                for (int n = 0; n < 4; ++n)
                    acc[m][n] = __builtin_amdgcn_mfma_f32_16x16x32_bf16(af[m], bfr[n], acc[m][n], 0, 0, 0);
        }
        __syncthreads();
    }
    const float s = scale_p[0];
    const int lq4 = (lane >> 4) * 4;
#pragma unroll
    for (int m = 0; m < 4; ++m)
#pragma unroll
        for (int n = 0; n < 4; ++n) {
            const int col = col0 + wn * 64 + n * 16 + lr;
            const float bv = bias[col];
#pragma unroll
            for (int j = 0; j < 4; ++j) {
                const int row = row0 + wm * 64 + m * 16 + lq4 + j;
                C[(size_t)row * N + col] = acc[m][n][j] * s + bv;
            }
        }
}

extern "C" void kernel_launch(void* const* d_in, const int* in_sizes, int n_in,
                              void* d_out, int out_size, void* d_ws, size_t ws_size,
                              hipStream_t stream) {
    const float* x     = (const float*)d_in[0];
    const int*   w8    = (const int*)d_in[1];
    const float* scale = (const float*)d_in[2];
    const float* bias  = (const float*)d_in[3];
    float* out = (float*)d_out;

    const int N = in_sizes[3];                    // 16384
    const int K = (int)((long)in_sizes[1] / N);   // 4096
    const int M = (int)((long)in_sizes[0] / K);   // 4096

    const size_t needA = (size_t)M * K * 2;
    const size_t needB = (size_t)N * K * 2;

    if (ws_size >= needA + needB) {
        unsigned short* Abf = (unsigned short*)d_ws;
        unsigned short* Bbf = (unsigned short*)((char*)d_ws + needA);
        cvt_x_kernel<<<2048, 256, 0, stream>>>(x, Abf, M * K / 8);
        cvt_w_kernel<<<2048, 256, 0, stream>>>(w8, Bbf, N * K / 8);
        const int NT = K / BK8;
        if (M % BM8 == 0 && N % BN8 == 0 && NT >= 4 && (NT & 1) == 0) {
            const int nblocks = (M / BM8) * (N / BN8);
            gemm8p<<<nblocks, 512, 0, stream>>>(Abf, Bbf, scale, bias, out, M, N, K);
        } else {
            const int nblocks = (M / BM) * (N / BN);
            gemm_bt<<<nblocks, 256, 0, stream>>>(Abf, Bbf, scale, bias, out, M, N, K);
        }
    } else {
        const int nblocks = (M / BM) * (N / BN);
        gemm_fused<<<nblocks, 256, 0, stream>>>(x, w8, scale, bias, out, M, N, K);
    }
}

// Round 3
// 557.974 us; speedup vs baseline: 1.9189x; 1.9189x over previous
//
#include <hip/hip_runtime.h>
#include <stdint.h>
#include <stddef.h>

// ---------- types ----------
typedef __attribute__((ext_vector_type(8))) short     bf16x8;
typedef __attribute__((ext_vector_type(4))) float     f32x4;
typedef __attribute__((ext_vector_type(4))) float     f32x4v;
typedef __attribute__((ext_vector_type(4))) int       i32x4;
typedef __attribute__((ext_vector_type(8))) unsigned short u16x8;
typedef __attribute__((ext_vector_type(4))) unsigned short u16x4;

__device__ __forceinline__ unsigned short f2bf(float f) {
    union { float f; unsigned u; } v; v.f = f;
    unsigned r = v.u + 0x7FFFu + ((v.u >> 16) & 1u);
    return (unsigned short)(r >> 16);
}

__device__ __forceinline__ void gload_lds16(const void* g, void* l) {
    __builtin_amdgcn_global_load_lds(
        (const __attribute__((address_space(1))) void*)(g),
        (__attribute__((address_space(3))) void*)(l), 16, 0, 0);
}

// ---------- convert kernels ----------
__global__ void cvt_x_kernel(const float* __restrict__ x, unsigned short* __restrict__ o, int n8) {
    int i = blockIdx.x * blockDim.x + threadIdx.x;
    int stride = gridDim.x * blockDim.x;
    for (; i < n8; i += stride) {
        f32x4v a = ((const f32x4v*)x)[2 * (size_t)i];
        f32x4v b = ((const f32x4v*)x)[2 * (size_t)i + 1];
        u16x8 r;
        r[0] = f2bf(a[0]); r[1] = f2bf(a[1]); r[2] = f2bf(a[2]); r[3] = f2bf(a[3]);
        r[4] = f2bf(b[0]); r[5] = f2bf(b[1]); r[6] = f2bf(b[2]); r[7] = f2bf(b[3]);
        ((u16x8*)o)[i] = r;
    }
}

__global__ void cvt_w_kernel(const int* __restrict__ w, unsigned short* __restrict__ o, int n8) {
    int i = blockIdx.x * blockDim.x + threadIdx.x;
    int stride = gridDim.x * blockDim.x;
    for (; i < n8; i += stride) {
        i32x4 a = ((const i32x4*)w)[2 * (size_t)i];
        i32x4 b = ((const i32x4*)w)[2 * (size_t)i + 1];
        u16x8 r;
        r[0] = f2bf((float)a[0]); r[1] = f2bf((float)a[1]);
        r[2] = f2bf((float)a[2]); r[3] = f2bf((float)a[3]);
        r[4] = f2bf((float)b[0]); r[5] = f2bf((float)b[1]);
        r[6] = f2bf((float)b[2]); r[7] = f2bf((float)b[3]);
        ((u16x8*)o)[i] = r;
    }
}

// =====================================================================
// 256x256 8-phase GEMM, v3: spill-free register schedule.
// Snake (m0-3,n0-1)->(m0-3,n2-3)->(m4-7,n2-3)->(m4-7,n0-1); B[n0-1]
// re-read in P4 so peak live frags = 48 VGPR (was 80 -> spilled in v2).
// Stage: P1->B0(t+1), P2->B1(t+1), P3->A0(t+2), P4->A1(t+2);
// vmcnt(4) once per tile at P4 (leaves A(t+2) in flight).
// Swizzle (both-sides): LDS[row][c16] = G[row][c16 ^ (row&7)] via
// pre-swizzled global source; reads XOR with (row&7)<<4.
// =====================================================================
#define BM8 256
#define BN8 256
#define BK8 64

__global__ __launch_bounds__(512, 2) void gemm8p(
    const unsigned short* __restrict__ A,   // [M][K] bf16
    const unsigned short* __restrict__ Bw,  // [N][K] bf16
    const float* __restrict__ scale_p,
    const float* __restrict__ bias,
    float* __restrict__ C,
    int M, int N, int K)
{
    __shared__ __align__(16) char smem[131072];

    const int t    = threadIdx.x;
    const int lane = t & 63;
    const int w    = t >> 6;     // 0..7
    const int wm   = w >> 2;     // 0..1  (M half)
    const int wn   = w & 3;      // 0..3  (N quarter)

    int nwg = gridDim.x, bid = blockIdx.x;
    int swz = ((nwg & 7) == 0) ? ((bid & 7) * (nwg >> 3) + (bid >> 3)) : bid;
    const int ntn  = N / BN8;
    const int row0 = (swz / ntn) * BM8;
    const int col0 = (swz % ntn) * BN8;

    const int Kb = K * 2;                    // row stride bytes
    const int NT = K / BK8;

    // staging geometry (per-lane): row srow, pre-swizzled 16B col
    const int srow = w * 8 + (lane >> 3);               // 0..63
    const int sc2  = ((lane & 7) ^ (lane >> 3)) * 16;   // swizzled col bytes
    const int ldsLaneOff = w * 1024 + lane * 16;        // linear dest

    const char* aG = (const char*)A + (size_t)(row0 + srow) * Kb + sc2;
    const char* bG = (const char*)Bw + (size_t)(col0 + srow) * Kb + sc2;

    // frag-read geometry
    const int q    = lane >> 4;        // 0..3 k-chunk
    const int lr   = lane & 15;        // row within 16
    const int swzr = (lr & 7) << 4;    // read-side XOR

    f32x4 acc[8][4] = {};
    bf16x8 aF[4][2], aS[4][2], bF[2][2], bS[2][2];

    // STAGE one 128-row half (2 x gload_lds16): half h of A or B, K-tile tj
#define STG(gbase, h, tj, buf, region) do {                                   \
    const char* _g = (gbase) + (size_t)(h) * 128 * Kb + (size_t)(tj) * 128;   \
    char* _l = &smem[(buf) * 65536 + (region) * 16384 + ldsLaneOff];          \
    gload_lds16(_g, _l);                                                      \
    gload_lds16(_g + (size_t)64 * Kb, _l + 8192);                             \
} while (0)

#define RDA(buf, mi, ks) \
    (*(const bf16x8*)&smem[(buf) * 65536 + wm * 16384 + ((mi) * 16 + lr) * 128 \
                           + ((((ks) << 6) | (q << 4)) ^ swzr)])
#define RDB(buf, nj, ks) \
    (*(const bf16x8*)&smem[(buf) * 65536 + (2 + (wn >> 1)) * 16384              \
                           + ((wn & 1) * 64 + (nj) * 16 + lr) * 128             \
                           + ((((ks) << 6) | (q << 4)) ^ swzr)])

#define MFMA_(a, b, c) (c) = __builtin_amdgcn_mfma_f32_16x16x32_bf16((a), (b), (c), 0, 0, 0)
#define BAR() __builtin_amdgcn_s_barrier()
#define LGKM0() do { asm volatile("s_waitcnt lgkmcnt(0)" ::: "memory"); \
                     __builtin_amdgcn_sched_barrier(0); } while (0)
#define VM4() asm volatile("s_waitcnt vmcnt(4)" ::: "memory")
#define VM0() asm volatile("s_waitcnt vmcnt(0)" ::: "memory")
#define VMNONE() do { } while (0)

#define TILE_STEP(tt, bb, stB, stA2, VMW) do {                                        \
    /* P1: read aF(8)+bF(4); stage B0(t+1); MFMA (m0-3 x n0-1) */                     \
    _Pragma("unroll") for (int mi = 0; mi < 4; ++mi) {                                \
        aF[mi][0] = RDA(bb, mi, 0); aF[mi][1] = RDA(bb, mi, 1); }                     \
    _Pragma("unroll") for (int nj = 0; nj < 2; ++nj) {                                \
        bF[nj][0] = RDB(bb, nj, 0); bF[nj][1] = RDB(bb, nj, 1); }                     \
    if (stB) STG(bG, 0, (tt) + 1, (bb) ^ 1, 2);                                       \
    BAR(); LGKM0();                                                                   \
    __builtin_amdgcn_s_setprio(1);                                                    \
    _Pragma("unroll") for (int mi = 0; mi < 4; ++mi)                                  \
    _Pragma("unroll") for (int nj = 0; nj < 2; ++nj) {                                \
        MFMA_(aF[mi][0], bF[nj][0], acc[mi][nj]);                                     \
        MFMA_(aF[mi][1], bF[nj][1], acc[mi][nj]); }                                   \
    __builtin_amdgcn_s_setprio(0);                                                    \
    BAR();                                                                            \
    /* P2: read bS(4); stage B1(t+1); MFMA (m0-3 x n2-3); aF dies here */             \
    _Pragma("unroll") for (int nj = 0; nj < 2; ++nj) {                                \
        bS[nj][0] = RDB(bb, 2 + nj, 0); bS[nj][1] = RDB(bb, 2 + nj, 1); }             \
    if (stB) STG(bG, 1, (tt) + 1, (bb) ^ 1, 3);                                       \
    BAR(); LGKM0();                                                                   \
    __builtin_amdgcn_s_setprio(1);                                                    \
    _Pragma("unroll") for (int mi = 0; mi < 4; ++mi)                                  \
    _Pragma("unroll") for (int nj = 0; nj < 2; ++nj) {                                \
        MFMA_(aF[mi][0], bS[nj][0], acc[mi][2 + nj]);                                 \
        MFMA_(aF[mi][1], bS[nj][1], acc[mi][2 + nj]); }                               \
    __builtin_amdgcn_s_setprio(0);                                                    \
    BAR();                                                                            \
    /* P3: read aS(8); stage A0(t+2); MFMA (m4-7 x n2-3); bS dies here */             \
    _Pragma("unroll") for (int mi = 0; mi < 4; ++mi) {                                \
        aS[mi][0] = RDA(bb, 4 + mi, 0); aS[mi][1] = RDA(bb, 4 + mi, 1); }             \
    if (stA2) STG(aG, 0, (tt) + 2, (bb), 0);                                          \
    BAR(); LGKM0();                                                                   \
    __builtin_amdgcn_s_setprio(1);                                                    \
    _Pragma("unroll") for (int mi = 0; mi < 4; ++mi)                                  \
    _Pragma("unroll") for (int nj = 0; nj < 2; ++nj) {                                \
        MFMA_(aS[mi][0], bS[nj][0], acc[4 + mi][2 + nj]);                             \
        MFMA_(aS[mi][1], bS[nj][1], acc[4 + mi][2 + nj]); }                           \
    __builtin_amdgcn_s_setprio(0);                                                    \
    BAR();                                                                            \
    /* P4: re-read bF(4); stage A1(t+2); MFMA (m4-7 x n0-1); tile vmcnt */            \
    _Pragma("unroll") for (int nj = 0; nj < 2; ++nj) {                                \
        bF[nj][0] = RDB(bb, nj, 0); bF[nj][1] = RDB(bb, nj, 1); }                     \
    if (stA2) STG(aG, 1, (tt) + 2, (bb), 1);                                          \
    BAR(); LGKM0();                                                                   \
    __builtin_amdgcn_s_setprio(1);                                                    \
    _Pragma("unroll") for (int mi = 0; mi < 4; ++mi)                                  \
    _Pragma("unroll") for (int nj = 0; nj < 2; ++nj) {                                \
        MFMA_(aS[mi][0], bF[nj][0], acc[4 + mi][nj]);                                 \
        MFMA_(aS[mi][1], bF[nj][1], acc[4 + mi][nj]); }                               \
    __builtin_amdgcn_s_setprio(0);                                                    \
    VMW();                                                                            \
    BAR();                                                                            \
} while (0)

    // prologue: tile0 {A0,A1,B0,B1} + tile1 {A0,A1}; vmcnt(4) -> tile0 resident
    STG(aG, 0, 0, 0, 0); STG(aG, 1, 0, 0, 1);
    STG(bG, 0, 0, 0, 2); STG(bG, 1, 0, 0, 3);
    STG(aG, 0, 1, 1, 0); STG(aG, 1, 1, 1, 1);
    VM4();
    BAR();

    for (int tt = 0; tt < NT - 2; tt += 2) {
        TILE_STEP(tt,     0, 1, 1, VM4);
        TILE_STEP(tt + 1, 1, 1, 1, VM4);
    }
    TILE_STEP(NT - 2, 0, 1, 0, VM0);     // stage B(NT-1) only; full drain
    TILE_STEP(NT - 1, 1, 0, 0, VMNONE);  // pure compute

    // ---- epilogue ----
    const float s = scale_p[0];
    float bv[4];
#pragma unroll
    for (int nj = 0; nj < 4; ++nj) bv[nj] = bias[col0 + wn * 64 + nj * 16 + lr];
#pragma unroll
    for (int mi = 0; mi < 8; ++mi) {
#pragma unroll
        for (int nj = 0; nj < 4; ++nj) {
            const int col = col0 + wn * 64 + nj * 16 + lr;
#pragma unroll
            for (int j = 0; j < 4; ++j) {
                const int row = row0 + wm * 128 + mi * 16 + q * 4 + j;
                C[(size_t)row * N + col] = acc[mi][nj][j] * s + bv[nj];
            }
        }
    }
#undef STG
#undef RDA
#undef RDB
#undef TILE_STEP
}

// ---------- fallback 128x128 (round-1, known-good 707us) ----------
#define BM 128
#define BN 128
#define BK 64

__global__ __launch_bounds__(256, 2) void gemm_bt(
    const unsigned short* __restrict__ A,
    const unsigned short* __restrict__ Bw,
    const float* __restrict__ scale_p,
    const float* __restrict__ bias,
    float* __restrict__ C,
    int M, int N, int K)
{
    __shared__ unsigned short As[BM * BK];
    __shared__ unsigned short Bs[BN * BK];

    const int t = threadIdx.x, lane = t & 63, w = t >> 6;
    const int wm = w >> 1, wn = w & 1;
    int nwg = gridDim.x, bid = blockIdx.x;
    int swz = (nwg % 8 == 0) ? ((bid & 7) * (nwg >> 3) + (bid >> 3)) : bid;
    const int ntn = N / BN;
    const int row0 = (swz / ntn) * BM, col0 = (swz % ntn) * BN;
    const int sr = t >> 3, sc = (t & 7) * 8;
    f32x4 acc[4][4] = {};
    const size_t ldK = (size_t)K;
    const int lr = lane & 15, lkbase = (lane >> 4) * 8;

    for (int kt = 0; kt < K; kt += BK) {
#pragma unroll
        for (int i = 0; i < 4; ++i)
            gload_lds16(A + (size_t)(row0 + i * 32 + sr) * ldK + kt + sc, &As[(i * 256 + t) * 8]);
#pragma unroll
        for (int i = 0; i < 4; ++i)
            gload_lds16(Bw + (size_t)(col0 + i * 32 + sr) * ldK + kt + sc, &Bs[(i * 256 + t) * 8]);
        __syncthreads();
#pragma unroll
        for (int ks = 0; ks < 2; ++ks) {
            const int lk = lkbase + ks * 32;
            bf16x8 af[4], bfr[4];
#pragma unroll
            for (int m = 0; m < 4; ++m) af[m] = *(const bf16x8*)&As[(wm * 64 + m * 16 + lr) * BK + lk];
#pragma unroll
            for (int n = 0; n < 4; ++n) bfr[n] = *(const bf16x8*)&Bs[(wn * 64 + n * 16 + lr) * BK + lk];
#pragma unroll
            for (int m = 0; m < 4; ++m)
#pragma unroll
                for (int n = 0; n < 4; ++n)
                    acc[m][n] = __builtin_amdgcn_mfma_f32_16x16x32_bf16(af[m], bfr[n], acc[m][n], 0, 0, 0);
        }
        __syncthreads();
    }
    const float s = scale_p[0];
    const int lq4 = (lane >> 4) * 4;
#pragma unroll
    for (int m = 0; m < 4; ++m)
#pragma unroll
        for (int n = 0; n < 4; ++n) {
            const int col = col0 + wn * 64 + n * 16 + lr;
            const float bv = bias[col];
#pragma unroll
            for (int j = 0; j < 4; ++j) {
                const int row = row0 + wm * 64 + m * 16 + lq4 + j;
                C[(size_t)row * N + col] = acc[m][n][j] * s + bv;
            }
        }
}

// ---------- fallback: fused convert-in-staging GEMM (ws too small) ----------
__global__ __launch_bounds__(256, 2) void gemm_fused(
    const float* __restrict__ A,
    const int* __restrict__ Bw,
    const float* __restrict__ scale_p,
    const float* __restrict__ bias,
    float* __restrict__ C,
    int M, int N, int K)
{
    __shared__ unsigned short As[BM * BK];
    __shared__ unsigned short Bs[BN * BK];
    const int t = threadIdx.x, lane = t & 63, w = t >> 6;
    const int wm = w >> 1, wn = w & 1;
    int nwg = gridDim.x, bid = blockIdx.x;
    int swz = (nwg % 8 == 0) ? ((bid & 7) * (nwg >> 3) + (bid >> 3)) : bid;
    const int ntn = N / BN;
    const int row0 = (swz / ntn) * BM, col0 = (swz % ntn) * BN;
    f32x4 acc[4][4] = {};
    const int lr = lane & 15, lkbase = (lane >> 4) * 8;

    for (int kt = 0; kt < K; kt += BK) {
#pragma unroll
        for (int i = 0; i < 8; ++i) {
            const int r = i * 16 + (t >> 4), c = (t & 15) * 4;
            f32x4v v = *(const f32x4v*)&A[(size_t)(row0 + r) * K + kt + c];
            u16x4 o; o[0] = f2bf(v[0]); o[1] = f2bf(v[1]); o[2] = f2bf(v[2]); o[3] = f2bf(v[3]);
            *(u16x4*)&As[r * BK + c] = o;
        }
#pragma unroll
        for (int i = 0; i < 8; ++i) {
            const int r = i * 16 + (t >> 4), c = (t & 15) * 4;
            i32x4 v = *(const i32x4*)&Bw[(size_t)(col0 + r) * K + kt + c];
            u16x4 o; o[0] = f2bf((float)v[0]); o[1] = f2bf((float)v[1]);
                     o[2] = f2bf((float)v[2]); o[3] = f2bf((float)v[3]);
            *(u16x4*)&Bs[r * BK + c] = o;
        }
        __syncthreads();
#pragma unroll
        for (int ks = 0; ks < 2; ++ks) {
            const int lk = lkbase + ks * 32;
            bf16x8 af[4], bfr[4];
#pragma unroll
            for (int m = 0; m < 4; ++m) af[m] = *(const bf16x8*)&As[(wm * 64 + m * 16 + lr) * BK + lk];
#pragma unroll
            for (int n = 0; n < 4; ++n) bfr[n] = *(const bf16x8*)&Bs[(wn * 64 + n * 16 + lr) * BK + lk];
#pragma unroll
            for (int m = 0; m < 4; ++m)
#pragma unroll
                for (int n = 0; n < 4; ++n)
                    acc[m][n] = __builtin_amdgcn_mfma_f32_16x16x32_bf16(af[m], bfr[n], acc[m][n], 0, 0, 0);
        }
        __syncthreads();
    }
    const float s = scale_p[0];
    const int lq4 = (lane >> 4) * 4;
#pragma unroll
    for (int m = 0; m < 4; ++m)
#pragma unroll
        for (int n = 0; n < 4; ++n) {
            const int col = col0 + wn * 64 + n * 16 + lr;
            const float bv = bias[col];
#pragma unroll
            for (int j = 0; j < 4; ++j) {
                const int row = row0 + wm * 64 + m * 16 + lq4 + j;
                C[(size_t)row * N + col] = acc[m][n][j] * s + bv;
            }
        }
}

extern "C" void kernel_launch(void* const* d_in, const int* in_sizes, int n_in,
                              void* d_out, int out_size, void* d_ws, size_t ws_size,
                              hipStream_t stream) {
    const float* x     = (const float*)d_in[0];
    const int*   w8    = (const int*)d_in[1];
    const float* scale = (const float*)d_in[2];
    const float* bias  = (const float*)d_in[3];
    float* out = (float*)d_out;

    const int N = in_sizes[3];                    // 16384
    const int K = (int)((long)in_sizes[1] / N);   // 4096
    const int M = (int)((long)in_sizes[0] / K);   // 4096

    const size_t needA = (size_t)M * K * 2;
    const size_t needB = (size_t)N * K * 2;

    if (ws_size >= needA + needB) {
        unsigned short* Abf = (unsigned short*)d_ws;
        unsigned short* Bbf = (unsigned short*)((char*)d_ws + needA);
        cvt_x_kernel<<<2048, 256, 0, stream>>>(x, Abf, M * K / 8);
        cvt_w_kernel<<<2048, 256, 0, stream>>>(w8, Bbf, N * K / 8);
        const int NT = K / BK8;
        if (M % BM8 == 0 && N % BN8 == 0 && NT >= 4 && (NT & 1) == 0) {
            const int nblocks = (M / BM8) * (N / BN8);
            gemm8p<<<nblocks, 512, 0, stream>>>(Abf, Bbf, scale, bias, out, M, N, K);
        } else {
            const int nblocks = (M / BM) * (N / BN);
            gemm_bt<<<nblocks, 256, 0, stream>>>(Abf, Bbf, scale, bias, out, M, N, K);
        }
    } else {
        const int nblocks = (M / BM) * (N / BN);
        gemm_fused<<<nblocks, 256, 0, stream>>>(x, w8, scale, bias, out, M, N, K);
    }
}

// Round 4
// 358.292 us; speedup vs baseline: 2.9883x; 1.5573x over previous
//
#include <hip/hip_runtime.h>
#include <stdint.h>
#include <stddef.h>

// ---------- types ----------
typedef __attribute__((ext_vector_type(4))) int       i32x4;   // 16B: MFMA i8 operand / i32 acc
typedef __attribute__((ext_vector_type(8))) short     bf16x8;
typedef __attribute__((ext_vector_type(4))) float     f32x4;
typedef __attribute__((ext_vector_type(4))) float     f32x4v;
typedef __attribute__((ext_vector_type(4))) unsigned short u16x4;

__device__ __forceinline__ unsigned short f2bf(float f) {
    union { float f; unsigned u; } v; v.f = f;
    unsigned r = v.u + 0x7FFFu + ((v.u >> 16) & 1u);
    return (unsigned short)(r >> 16);
}

__device__ __forceinline__ void gload_lds16(const void* g, void* l) {
    __builtin_amdgcn_global_load_lds(
        (const __attribute__((address_space(1))) void*)(g),
        (__attribute__((address_space(3))) void*)(l), 16, 0, 0);
}

__device__ __forceinline__ int pack4(float a, float b, float c, float d, float inv) {
    int r0 = ((int)rintf(a * inv)) & 255;
    int r1 = ((int)rintf(b * inv)) & 255;
    int r2 = ((int)rintf(c * inv)) & 255;
    int r3 = ((int)rintf(d * inv)) & 255;
    return r0 | (r1 << 8) | (r2 << 16) | (r3 << 24);
}

// ---------- convert: x fp32 -> int8 per-row dynamic quant (+ sx per row) ----------
__global__ void cvt_x_q8(const float* __restrict__ x, signed char* __restrict__ xq,
                         float* __restrict__ sx, int K) {
    const int row = blockIdx.x;
    const int t   = threadIdx.x;          // 256 threads; K/1024 groups of f32x4 each
    const float* xr = x + (size_t)row * K;
    const int ng = K / 1024;              // f32x4 groups per thread (K=4096 -> 4)

    f32x4v v[8];
    float am = 0.f;
#pragma unroll
    for (int i = 0; i < 8; ++i) {
        if (i < ng) {
            v[i] = ((const f32x4v*)xr)[i * 256 + t];
            am = fmaxf(am, fmaxf(fmaxf(fabsf(v[i][0]), fabsf(v[i][1])),
                                 fmaxf(fabsf(v[i][2]), fabsf(v[i][3]))));
        }
    }
    // wave reduce (64 lanes)
#pragma unroll
    for (int m = 32; m >= 1; m >>= 1) am = fmaxf(am, __shfl_xor(am, m, 64));
    __shared__ float red[4];
    const int w = t >> 6;
    if ((t & 63) == 0) red[w] = am;
    __syncthreads();
    am = fmaxf(fmaxf(red[0], red[1]), fmaxf(red[2], red[3]));

    const float inv = (am > 0.f) ? 127.0f / am : 0.f;
    if (t == 0) sx[row] = (am > 0.f) ? am / 127.0f : 0.f;

    int* oq = (int*)(xq + (size_t)row * K);
#pragma unroll
    for (int i = 0; i < 8; ++i)
        if (i < ng) oq[i * 256 + t] = pack4(v[i][0], v[i][1], v[i][2], v[i][3], inv);
}

// ---------- convert: W int32 -> int8 (values already int8-ranged; exact) ----------
__global__ void cvt_w_q8(const int* __restrict__ w, signed char* __restrict__ o, int n4) {
    int i = blockIdx.x * blockDim.x + threadIdx.x;
    int stride = gridDim.x * blockDim.x;
    for (; i < n4; i += stride) {
        i32x4 a = ((const i32x4*)w)[i];
        ((int*)o)[i] = (a[0] & 255) | ((a[1] & 255) << 8) | ((a[2] & 255) << 16) | ((a[3] & 255) << 24);
    }
}

// =====================================================================
// 256x256 8-phase int8 GEMM (v4). Same byte-level schedule as proven v3:
// BK=128 i8 elems = 128B LDS rows (identical addressing/swizzle), NT=K/128,
// mfma_i32_16x16x64_i8 (2x bf16 rate, exact i32 accum).
// Snake (m0-3,n0-1)->(m0-3,n2-3)->(m4-7,n2-3)->(m4-7,n0-1); bF re-read P4.
// Stage: P1->B0(t+1), P2->B1(t+1), P3->A0(t+2), P4->A1(t+2); vmcnt(4)@P4.
// Swizzle both-sides: LDS[row][c16]=G[row][c16^(row&7)] (pre-swz source),
// reads XOR (row&7)<<4. Epilogue: y = acc * sx[row]*s + bias[col].
// =====================================================================
#define BM8 256
#define BN8 256
#define BKQ 128   // int8 elems per K-tile (=128 bytes)

__global__ __launch_bounds__(512, 2) void gemm8p_i8(
    const signed char* __restrict__ A,   // [M][K] i8
    const signed char* __restrict__ Bw,  // [N][K] i8
    const float* __restrict__ sx,        // [M] per-row x scale
    const float* __restrict__ scale_p,
    const float* __restrict__ bias,
    float* __restrict__ C,
    int M, int N, int K)
{
    __shared__ __align__(16) char smem[131072];

    const int t    = threadIdx.x;
    const int lane = t & 63;
    const int w    = t >> 6;
    const int wm   = w >> 2;
    const int wn   = w & 3;

    int nwg = gridDim.x, bid = blockIdx.x;
    int swz = ((nwg & 7) == 0) ? ((bid & 7) * (nwg >> 3) + (bid >> 3)) : bid;
    const int ntn  = N / BN8;
    const int row0 = (swz / ntn) * BM8;
    const int col0 = (swz % ntn) * BN8;

    const int Kb = K;                // row stride BYTES (i8)
    const int NT = K / BKQ;

    const int srow = w * 8 + (lane >> 3);
    const int sc2  = ((lane & 7) ^ (lane >> 3)) * 16;
    const int ldsLaneOff = w * 1024 + lane * 16;

    const char* aG = (const char*)A + (size_t)(row0 + srow) * Kb + sc2;
    const char* bG = (const char*)Bw + (size_t)(col0 + srow) * Kb + sc2;

    const int q    = lane >> 4;
    const int lr   = lane & 15;
    const int swzr = (lr & 7) << 4;

    i32x4 acc[8][4] = {};
    i32x4 aF[4][2], aS[4][2], bF[2][2], bS[2][2];

#define STG(gbase, h, tj, buf, region) do {                                   \
    const char* _g = (gbase) + (size_t)(h) * 128 * Kb + (size_t)(tj) * 128;   \
    char* _l = &smem[(buf) * 65536 + (region) * 16384 + ldsLaneOff];          \
    gload_lds16(_g, _l);                                                      \
    gload_lds16(_g + (size_t)64 * Kb, _l + 8192);                             \
} while (0)

#define RDA(buf, mi, ks) \
    (*(const i32x4*)&smem[(buf) * 65536 + wm * 16384 + ((mi) * 16 + lr) * 128 \
                          + ((((ks) << 6) | (q << 4)) ^ swzr)])
#define RDB(buf, nj, ks) \
    (*(const i32x4*)&smem[(buf) * 65536 + (2 + (wn >> 1)) * 16384              \
                          + ((wn & 1) * 64 + (nj) * 16 + lr) * 128             \
                          + ((((ks) << 6) | (q << 4)) ^ swzr)])

#define MFMA_(a, b, c) (c) = __builtin_amdgcn_mfma_i32_16x16x64_i8((a), (b), (c), 0, 0, 0)
#define BAR() __builtin_amdgcn_s_barrier()
#define LGKM0() do { asm volatile("s_waitcnt lgkmcnt(0)" ::: "memory"); \
                     __builtin_amdgcn_sched_barrier(0); } while (0)
#define VM4() asm volatile("s_waitcnt vmcnt(4)" ::: "memory")
#define VM0() asm volatile("s_waitcnt vmcnt(0)" ::: "memory")
#define VMNONE() do { } while (0)

#define TILE_STEP(tt, bb, stB, stA2, VMW) do {                                        \
    /* P1: read aF(8)+bF(4); stage B0(t+1); MFMA (m0-3 x n0-1) */                     \
    _Pragma("unroll") for (int mi = 0; mi < 4; ++mi) {                                \
        aF[mi][0] = RDA(bb, mi, 0); aF[mi][1] = RDA(bb, mi, 1); }                     \
    _Pragma("unroll") for (int nj = 0; nj < 2; ++nj) {                                \
        bF[nj][0] = RDB(bb, nj, 0); bF[nj][1] = RDB(bb, nj, 1); }                     \
    if (stB) STG(bG, 0, (tt) + 1, (bb) ^ 1, 2);                                       \
    BAR(); LGKM0();                                                                   \
    __builtin_amdgcn_s_setprio(1);                                                    \
    _Pragma("unroll") for (int mi = 0; mi < 4; ++mi)                                  \
    _Pragma("unroll") for (int nj = 0; nj < 2; ++nj) {                                \
        MFMA_(aF[mi][0], bF[nj][0], acc[mi][nj]);                                     \
        MFMA_(aF[mi][1], bF[nj][1], acc[mi][nj]); }                                   \
    __builtin_amdgcn_s_setprio(0);                                                    \
    BAR();                                                                            \
    /* P2: read bS(4); stage B1(t+1); MFMA (m0-3 x n2-3) */                           \
    _Pragma("unroll") for (int nj = 0; nj < 2; ++nj) {                                \
        bS[nj][0] = RDB(bb, 2 + nj, 0); bS[nj][1] = RDB(bb, 2 + nj, 1); }             \
    if (stB) STG(bG, 1, (tt) + 1, (bb) ^ 1, 3);                                       \
    BAR(); LGKM0();                                                                   \
    __builtin_amdgcn_s_setprio(1);                                                    \
    _Pragma("unroll") for (int mi = 0; mi < 4; ++mi)                                  \
    _Pragma("unroll") for (int nj = 0; nj < 2; ++nj) {                                \
        MFMA_(aF[mi][0], bS[nj][0], acc[mi][2 + nj]);                                 \
        MFMA_(aF[mi][1], bS[nj][1], acc[mi][2 + nj]); }                               \
    __builtin_amdgcn_s_setprio(0);                                                    \
    BAR();                                                                            \
    /* P3: read aS(8); stage A0(t+2); MFMA (m4-7 x n2-3) */                           \
    _Pragma("unroll") for (int mi = 0; mi < 4; ++mi) {                                \
        aS[mi][0] = RDA(bb, 4 + mi, 0); aS[mi][1] = RDA(bb, 4 + mi, 1); }             \
    if (stA2) STG(aG, 0, (tt) + 2, (bb), 0);                                          \
    BAR(); LGKM0();                                                                   \
    __builtin_amdgcn_s_setprio(1);                                                    \
    _Pragma("unroll") for (int mi = 0; mi < 4; ++mi)                                  \
    _Pragma("unroll") for (int nj = 0; nj < 2; ++nj) {                                \
        MFMA_(aS[mi][0], bS[nj][0], acc[4 + mi][2 + nj]);                             \
        MFMA_(aS[mi][1], bS[nj][1], acc[4 + mi][2 + nj]); }                           \
    __builtin_amdgcn_s_setprio(0);                                                    \
    BAR();                                                                            \
    /* P4: re-read bF(4); stage A1(t+2); MFMA (m4-7 x n0-1); tile vmcnt */            \
    _Pragma("unroll") for (int nj = 0; nj < 2; ++nj) {                                \
        bF[nj][0] = RDB(bb, nj, 0); bF[nj][1] = RDB(bb, nj, 1); }                     \
    if (stA2) STG(aG, 1, (tt) + 2, (bb), 1);                                          \
    BAR(); LGKM0();                                                                   \
    __builtin_amdgcn_s_setprio(1);                                                    \
    _Pragma("unroll") for (int mi = 0; mi < 4; ++mi)                                  \
    _Pragma("unroll") for (int nj = 0; nj < 2; ++nj) {                                \
        MFMA_(aS[mi][0], bF[nj][0], acc[4 + mi][nj]);                                 \
        MFMA_(aS[mi][1], bF[nj][1], acc[4 + mi][nj]); }                               \
    __builtin_amdgcn_s_setprio(0);                                                    \
    VMW();                                                                            \
    BAR();                                                                            \
} while (0)

    // prologue: tile0 {A0,A1,B0,B1} + tile1 {A0,A1}; vmcnt(4) -> tile0 resident
    STG(aG, 0, 0, 0, 0); STG(aG, 1, 0, 0, 1);
    STG(bG, 0, 0, 0, 2); STG(bG, 1, 0, 0, 3);
    STG(aG, 0, 1, 1, 0); STG(aG, 1, 1, 1, 1);
    VM4();
    BAR();

    for (int tt = 0; tt < NT - 2; tt += 2) {
        TILE_STEP(tt,     0, 1, 1, VM4);
        TILE_STEP(tt + 1, 1, 1, 1, VM4);
    }
    TILE_STEP(NT - 2, 0, 1, 0, VM0);
    TILE_STEP(NT - 1, 1, 0, 0, VMNONE);

    // ---- epilogue: y = acc * (sx[row]*s) + bias[col] ----
    const float s = scale_p[0];
    float bv[4];
#pragma unroll
    for (int nj = 0; nj < 4; ++nj) bv[nj] = bias[col0 + wn * 64 + nj * 16 + lr];
#pragma unroll
    for (int mi = 0; mi < 8; ++mi) {
        const int rbase = row0 + wm * 128 + mi * 16 + q * 4;
        float sxr[4];
#pragma unroll
        for (int j = 0; j < 4; ++j) sxr[j] = sx[rbase + j] * s;
#pragma unroll
        for (int nj = 0; nj < 4; ++nj) {
            const int col = col0 + wn * 64 + nj * 16 + lr;
#pragma unroll
            for (int j = 0; j < 4; ++j)
                C[(size_t)(rbase + j) * N + col] = (float)acc[mi][nj][j] * sxr[j] + bv[nj];
        }
    }
#undef STG
#undef RDA
#undef RDB
#undef TILE_STEP
}

// ---------- fallback: fused fp32->bf16-in-staging GEMM (ws too small / odd shape) ----------
#define BM 128
#define BN 128
#define BK 64

__global__ __launch_bounds__(256, 2) void gemm_fused(
    const float* __restrict__ A,
    const int* __restrict__ Bw,
    const float* __restrict__ scale_p,
    const float* __restrict__ bias,
    float* __restrict__ C,
    int M, int N, int K)
{
    __shared__ unsigned short As[BM * BK];
    __shared__ unsigned short Bs[BN * BK];
    const int t = threadIdx.x, lane = t & 63, w = t >> 6;
    const int wm = w >> 1, wn = w & 1;
    int nwg = gridDim.x, bid = blockIdx.x;
    int swz = (nwg % 8 == 0) ? ((bid & 7) * (nwg >> 3) + (bid >> 3)) : bid;
    const int ntn = N / BN;
    const int row0 = (swz / ntn) * BM, col0 = (swz % ntn) * BN;
    f32x4 acc[4][4] = {};
    const int lr = lane & 15, lkbase = (lane >> 4) * 8;

    for (int kt = 0; kt < K; kt += BK) {
#pragma unroll
        for (int i = 0; i < 8; ++i) {
            const int r = i * 16 + (t >> 4), c = (t & 15) * 4;
            f32x4v v = *(const f32x4v*)&A[(size_t)(row0 + r) * K + kt + c];
            u16x4 o; o[0] = f2bf(v[0]); o[1] = f2bf(v[1]); o[2] = f2bf(v[2]); o[3] = f2bf(v[3]);
            *(u16x4*)&As[r * BK + c] = o;
        }
#pragma unroll
        for (int i = 0; i < 8; ++i) {
            const int r = i * 16 + (t >> 4), c = (t & 15) * 4;
            i32x4 v = *(const i32x4*)&Bw[(size_t)(col0 + r) * K + kt + c];
            u16x4 o; o[0] = f2bf((float)v[0]); o[1] = f2bf((float)v[1]);
                     o[2] = f2bf((float)v[2]); o[3] = f2bf((float)v[3]);
            *(u16x4*)&Bs[r * BK + c] = o;
        }
        __syncthreads();
#pragma unroll
        for (int ks = 0; ks < 2; ++ks) {
            const int lk = lkbase + ks * 32;
            bf16x8 af[4], bfr[4];
#pragma unroll
            for (int m = 0; m < 4; ++m) af[m] = *(const bf16x8*)&As[(wm * 64 + m * 16 + lr) * BK + lk];
#pragma unroll
            for (int n = 0; n < 4; ++n) bfr[n] = *(const bf16x8*)&Bs[(wn * 64 + n * 16 + lr) * BK + lk];
#pragma unroll
            for (int m = 0; m < 4; ++m)
#pragma unroll
                for (int n = 0; n < 4; ++n)
                    acc[m][n] = __builtin_amdgcn_mfma_f32_16x16x32_bf16(af[m], bfr[n], acc[m][n], 0, 0, 0);
        }
        __syncthreads();
    }
    const float s = scale_p[0];
    const int lq4 = (lane >> 4) * 4;
#pragma unroll
    for (int m = 0; m < 4; ++m)
#pragma unroll
        for (int n = 0; n < 4; ++n) {
            const int col = col0 + wn * 64 + n * 16 + lr;
            const float bv = bias[col];
#pragma unroll
            for (int j = 0; j < 4; ++j) {
                const int row = row0 + wm * 64 + m * 16 + lq4 + j;
                C[(size_t)row * N + col] = acc[m][n][j] * s + bv;
            }
        }
}

extern "C" void kernel_launch(void* const* d_in, const int* in_sizes, int n_in,
                              void* d_out, int out_size, void* d_ws, size_t ws_size,
                              hipStream_t stream) {
    const float* x     = (const float*)d_in[0];
    const int*   w8    = (const int*)d_in[1];
    const float* scale = (const float*)d_in[2];
    const float* bias  = (const float*)d_in[3];
    float* out = (float*)d_out;

    const int N = in_sizes[3];                    // 16384
    const int K = (int)((long)in_sizes[1] / N);   // 4096
    const int M = (int)((long)in_sizes[0] / K);   // 4096

    const size_t needA = (size_t)M * K;           // i8
    const size_t needB = (size_t)N * K;           // i8
    const size_t needS = (size_t)M * sizeof(float);
    const int NT = K / BKQ;

    const bool okShape = (M % BM8 == 0) && (N % BN8 == 0) && (K % BKQ == 0) &&
                         (K % 1024 == 0) && (K / 1024 <= 8) &&
                         (NT >= 4) && ((NT & 1) == 0);

    if (okShape && ws_size >= needA + needB + needS) {
        signed char* Aq = (signed char*)d_ws;
        signed char* Bq = Aq + needA;
        float*       sx = (float*)(Bq + needB);
        cvt_x_q8<<<M, 256, 0, stream>>>(x, Aq, sx, K);
        cvt_w_q8<<<4096, 256, 0, stream>>>(w8, Bq, (int)((size_t)N * K / 4));
        const int nblocks = (M / BM8) * (N / BN8);
        gemm8p_i8<<<nblocks, 512, 0, stream>>>(Aq, Bq, sx, scale, bias, out, M, N, K);
    } else {
        const int nblocks = (M / BM) * (N / BN);
        gemm_fused<<<nblocks, 256, 0, stream>>>(x, w8, scale, bias, out, M, N, K);
    }
}

// Round 5
// 341.130 us; speedup vs baseline: 3.1386x; 1.0503x over previous
//
#include <hip/hip_runtime.h>
#include <stdint.h>
#include <stddef.h>

// ---------- types ----------
typedef __attribute__((ext_vector_type(4))) int       i32x4;   // 16B: MFMA i8 operand / i32 acc
typedef __attribute__((ext_vector_type(8))) short     bf16x8;
typedef __attribute__((ext_vector_type(4))) float     f32x4;
typedef __attribute__((ext_vector_type(4))) float     f32x4v;
typedef __attribute__((ext_vector_type(4))) unsigned short u16x4;

__device__ __forceinline__ unsigned short f2bf(float f) {
    union { float f; unsigned u; } v; v.f = f;
    unsigned r = v.u + 0x7FFFu + ((v.u >> 16) & 1u);
    return (unsigned short)(r >> 16);
}

__device__ __forceinline__ void gload_lds16(const void* g, void* l) {
    __builtin_amdgcn_global_load_lds(
        (const __attribute__((address_space(1))) void*)(g),
        (__attribute__((address_space(3))) void*)(l), 16, 0, 0);
}

__device__ __forceinline__ int pack4(float a, float b, float c, float d, float inv) {
    int r0 = ((int)rintf(a * inv)) & 255;
    int r1 = ((int)rintf(b * inv)) & 255;
    int r2 = ((int)rintf(c * inv)) & 255;
    int r3 = ((int)rintf(d * inv)) & 255;
    return r0 | (r1 << 8) | (r2 << 16) | (r3 << 24);
}

// ---------- convert: x fp32 -> int8 per-row dynamic quant (+ sx per row) ----------
__global__ void cvt_x_q8(const float* __restrict__ x, signed char* __restrict__ xq,
                         float* __restrict__ sx, int K) {
    const int row = blockIdx.x;
    const int t   = threadIdx.x;          // 256 threads
    const float* xr = x + (size_t)row * K;
    const int ng = K / 1024;              // f32x4 groups per thread (K=4096 -> 4)

    f32x4v v[8];
    float am = 0.f;
#pragma unroll
    for (int i = 0; i < 8; ++i) {
        if (i < ng) {
            v[i] = __builtin_nontemporal_load(&((const f32x4v*)xr)[i * 256 + t]);
            am = fmaxf(am, fmaxf(fmaxf(fabsf(v[i][0]), fabsf(v[i][1])),
                                 fmaxf(fabsf(v[i][2]), fabsf(v[i][3]))));
        }
    }
#pragma unroll
    for (int m = 32; m >= 1; m >>= 1) am = fmaxf(am, __shfl_xor(am, m, 64));
    __shared__ float red[4];
    const int w = t >> 6;
    if ((t & 63) == 0) red[w] = am;
    __syncthreads();
    am = fmaxf(fmaxf(red[0], red[1]), fmaxf(red[2], red[3]));

    const float inv = (am > 0.f) ? 127.0f / am : 0.f;
    if (t == 0) sx[row] = (am > 0.f) ? am / 127.0f : 0.f;

    int* oq = (int*)(xq + (size_t)row * K);
#pragma unroll
    for (int i = 0; i < 8; ++i)
        if (i < ng) oq[i * 256 + t] = pack4(v[i][0], v[i][1], v[i][2], v[i][3], inv);
}

// ---------- convert: W int32 -> int8 (values already int8-ranged; exact) ----------
__global__ void cvt_w_q8(const int* __restrict__ w, signed char* __restrict__ o, int n4) {
    int i = blockIdx.x * blockDim.x + threadIdx.x;
    int stride = gridDim.x * blockDim.x;
    for (; i < n4; i += stride) {
        i32x4 a = __builtin_nontemporal_load(&((const i32x4*)w)[i]);
        ((int*)o)[i] = (a[0] & 255) | ((a[1] & 255) << 8) | ((a[2] & 255) << 16) | ((a[3] & 255) << 24);
    }
}

// =====================================================================
// 256x256 int8 GEMM v5: 2-barrier-per-K-tile, compiler-scheduled tile body.
// vs v4: dropped 6 intra-tile barriers + explicit lgkm fences (compiler
// emits fine-grained lgkmcnt(N)); counted vmcnt(4) kept (never drain);
// A(t+2) staging moved AFTER the mid-tile barrier (fixes v4's latent
// P3-read vs P3-stage race); C stored nontemporal (stop evicting B
// panels from L3 -> FETCH_SIZE should collapse toward compulsory 80MB).
// Hazard audit (all LDS write-vs-read pairs):
//   STG B0(t+1)->bb^1.B0 @P1: last reads of bb^1.B0 = t-1 P4, complete
//     before boundary BAR (consumer MFMAs precede BAR).            SAFE
//   STG B1(t+1)->bb^1.B1 @P2: last reads t-1 P2/P3 < boundary BAR. SAFE
//   STG A(t+2)->bb.A @P4: last reads of bb.A = tile t P1/P3, all
//     complete chip-wide at mid BAR; STG issued after mid BAR.     SAFE
//   Reads of bb^1 (next tile) cannot hoist above VM4 ("memory" asm)
//     + boundary BAR; VM4+BAR ensure staging landed.               SAFE
// vmcnt ledger (steady state, 2 loads/STG): at tile entry 4 in flight
// (A(t+1)); +B(t+1) 4 +A(t+2) 4 = 12; VM4 -> A(t+1),B(t+1) landed,
// A(t+2) flying. Identical to v4's proven ledger.
// =====================================================================
#define BM8 256
#define BN8 256
#define BKQ 128   // int8 elems per K-tile (=128 bytes, same row geometry as v3/v4)

__global__ __launch_bounds__(512, 2) void gemm8p_i8(
    const signed char* __restrict__ A,   // [M][K] i8
    const signed char* __restrict__ Bw,  // [N][K] i8
    const float* __restrict__ sx,        // [M] per-row x scale
    const float* __restrict__ scale_p,
    const float* __restrict__ bias,
    float* __restrict__ C,
    int M, int N, int K)
{
    __shared__ __align__(16) char smem[131072];

    const int t    = threadIdx.x;
    const int lane = t & 63;
    const int w    = t >> 6;
    const int wm   = w >> 2;
    const int wn   = w & 3;

    int nwg = gridDim.x, bid = blockIdx.x;
    int swz = ((nwg & 7) == 0) ? ((bid & 7) * (nwg >> 3) + (bid >> 3)) : bid;
    const int ntn  = N / BN8;
    const int row0 = (swz / ntn) * BM8;
    const int col0 = (swz % ntn) * BN8;

    const int Kb = K;                // row stride BYTES (i8)
    const int NT = K / BKQ;

    const int srow = w * 8 + (lane >> 3);
    const int sc2  = ((lane & 7) ^ (lane >> 3)) * 16;
    const int ldsLaneOff = w * 1024 + lane * 16;

    const char* aG = (const char*)A + (size_t)(row0 + srow) * Kb + sc2;
    const char* bG = (const char*)Bw + (size_t)(col0 + srow) * Kb + sc2;

    const int q    = lane >> 4;
    const int lr   = lane & 15;
    const int swzr = (lr & 7) << 4;

    i32x4 acc[8][4] = {};
    i32x4 aF[4][2], aS[4][2], bF[2][2], bS[2][2];

#define STG(gbase, h, tj, buf, region) do {                                   \
    const char* _g = (gbase) + (size_t)(h) * 128 * Kb + (size_t)(tj) * 128;   \
    char* _l = &smem[(buf) * 65536 + (region) * 16384 + ldsLaneOff];          \
    gload_lds16(_g, _l);                                                      \
    gload_lds16(_g + (size_t)64 * Kb, _l + 8192);                             \
} while (0)

#define RDA(buf, mi, ks) \
    (*(const i32x4*)&smem[(buf) * 65536 + wm * 16384 + ((mi) * 16 + lr) * 128 \
                          + ((((ks) << 6) | (q << 4)) ^ swzr)])
#define RDB(buf, nj, ks) \
    (*(const i32x4*)&smem[(buf) * 65536 + (2 + (wn >> 1)) * 16384              \
                          + ((wn & 1) * 64 + (nj) * 16 + lr) * 128             \
                          + ((((ks) << 6) | (q << 4)) ^ swzr)])

#define MFMA_(a, b, c) (c) = __builtin_amdgcn_mfma_i32_16x16x64_i8((a), (b), (c), 0, 0, 0)
#define BAR() __builtin_amdgcn_s_barrier()
#define FENCE() asm volatile("" ::: "memory")
#define VM4() asm volatile("s_waitcnt vmcnt(4)" ::: "memory")
#define VM0() asm volatile("s_waitcnt vmcnt(0)" ::: "memory")
#define VMNONE() do { } while (0)

// One K-tile: phases P1..P3 | mid BAR | P4 | VM | boundary BAR.
// Compiler schedules freely inside each barrier-bounded region; it inserts
// fine-grained lgkmcnt before each MFMA operand use (no manual drains).
#define TILE_STEP(tt, bb, stB, stA2, VMW) do {                                        \
    /* P1: aF+bF reads; stage B0(t+1); MFMA (m0-3 x n0-1) */                          \
    _Pragma("unroll") for (int mi = 0; mi < 4; ++mi) {                                \
        aF[mi][0] = RDA(bb, mi, 0); aF[mi][1] = RDA(bb, mi, 1); }                     \
    _Pragma("unroll") for (int nj = 0; nj < 2; ++nj) {                                \
        bF[nj][0] = RDB(bb, nj, 0); bF[nj][1] = RDB(bb, nj, 1); }                     \
    if (stB) STG(bG, 0, (tt) + 1, (bb) ^ 1, 2);                                       \
    __builtin_amdgcn_s_setprio(1);                                                    \
    _Pragma("unroll") for (int mi = 0; mi < 4; ++mi)                                  \
    _Pragma("unroll") for (int nj = 0; nj < 2; ++nj) {                                \
        MFMA_(aF[mi][0], bF[nj][0], acc[mi][nj]);                                     \
        MFMA_(aF[mi][1], bF[nj][1], acc[mi][nj]); }                                   \
    __builtin_amdgcn_s_setprio(0);                                                    \
    /* P2: bS reads; stage B1(t+1); MFMA (m0-3 x n2-3) */                             \
    _Pragma("unroll") for (int nj = 0; nj < 2; ++nj) {                                \
        bS[nj][0] = RDB(bb, 2 + nj, 0); bS[nj][1] = RDB(bb, 2 + nj, 1); }             \
    if (stB) STG(bG, 1, (tt) + 1, (bb) ^ 1, 3);                                       \
    __builtin_amdgcn_s_setprio(1);                                                    \
    _Pragma("unroll") for (int mi = 0; mi < 4; ++mi)                                  \
    _Pragma("unroll") for (int nj = 0; nj < 2; ++nj) {                                \
        MFMA_(aF[mi][0], bS[nj][0], acc[mi][2 + nj]);                                 \
        MFMA_(aF[mi][1], bS[nj][1], acc[mi][2 + nj]); }                               \
    __builtin_amdgcn_s_setprio(0);                                                    \
    /* P3: aS reads; MFMA (m4-7 x n2-3) */                                            \
    _Pragma("unroll") for (int mi = 0; mi < 4; ++mi) {                                \
        aS[mi][0] = RDA(bb, 4 + mi, 0); aS[mi][1] = RDA(bb, 4 + mi, 1); }             \
    __builtin_amdgcn_s_setprio(1);                                                    \
    _Pragma("unroll") for (int mi = 0; mi < 4; ++mi)                                  \
    _Pragma("unroll") for (int nj = 0; nj < 2; ++nj) {                                \
        MFMA_(aS[mi][0], bS[nj][0], acc[4 + mi][2 + nj]);                             \
        MFMA_(aS[mi][1], bS[nj][1], acc[4 + mi][2 + nj]); }                           \
    __builtin_amdgcn_s_setprio(0);                                                    \
    BAR(); FENCE();   /* mid: all P1-P3 reads of bb.A complete chip-wide */           \
    /* P4: bF re-read; stage A0,A1(t+2) into bb (now provably safe); MFMA */          \
    _Pragma("unroll") for (int nj = 0; nj < 2; ++nj) {                                \
        bF[nj][0] = RDB(bb, nj, 0); bF[nj][1] = RDB(bb, nj, 1); }                     \
    if (stA2) { STG(aG, 0, (tt) + 2, (bb), 0); STG(aG, 1, (tt) + 2, (bb), 1); }       \
    __builtin_amdgcn_s_setprio(1);                                                    \
    _Pragma("unroll") for (int mi = 0; mi < 4; ++mi)                                  \
    _Pragma("unroll") for (int nj = 0; nj < 2; ++nj) {                                \
        MFMA_(aS[mi][0], bF[nj][0], acc[4 + mi][nj]);                                 \
        MFMA_(aS[mi][1], bF[nj][1], acc[4 + mi][nj]); }                               \
    __builtin_amdgcn_s_setprio(0);                                                    \
    VMW();                                                                            \
    BAR(); FENCE();   /* boundary: tile t+1 staging landed for all waves */           \
} while (0)

    // prologue: tile0 {A0,A1,B0,B1} + tile1 {A0,A1}; vmcnt(4) -> tile0 resident
    STG(aG, 0, 0, 0, 0); STG(aG, 1, 0, 0, 1);
    STG(bG, 0, 0, 0, 2); STG(bG, 1, 0, 0, 3);
    STG(aG, 0, 1, 1, 0); STG(aG, 1, 1, 1, 1);
    VM4();
    BAR(); FENCE();

    for (int tt = 0; tt < NT - 2; tt += 2) {
        TILE_STEP(tt,     0, 1, 1, VM4);
        TILE_STEP(tt + 1, 1, 1, 1, VM4);
    }
    TILE_STEP(NT - 2, 0, 1, 0, VM0);
    TILE_STEP(NT - 1, 1, 0, 0, VMNONE);

    // ---- epilogue: y = acc * (sx[row]*s) + bias[col]; nontemporal C stores ----
    const float s = scale_p[0];
    float bv[4];
#pragma unroll
    for (int nj = 0; nj < 4; ++nj) bv[nj] = bias[col0 + wn * 64 + nj * 16 + lr];
#pragma unroll
    for (int mi = 0; mi < 8; ++mi) {
        const int rbase = row0 + wm * 128 + mi * 16 + q * 4;
        float sxr[4];
#pragma unroll
        for (int j = 0; j < 4; ++j) sxr[j] = sx[rbase + j] * s;
#pragma unroll
        for (int nj = 0; nj < 4; ++nj) {
            const int col = col0 + wn * 64 + nj * 16 + lr;
#pragma unroll
            for (int j = 0; j < 4; ++j)
                __builtin_nontemporal_store((float)acc[mi][nj][j] * sxr[j] + bv[nj],
                                            &C[(size_t)(rbase + j) * N + col]);
        }
    }
#undef STG
#undef RDA
#undef RDB
#undef TILE_STEP
}

// ---------- fallback: fused fp32->bf16-in-staging GEMM (ws too small / odd shape) ----------
#define BM 128
#define BN 128
#define BK 64

__global__ __launch_bounds__(256, 2) void gemm_fused(
    const float* __restrict__ A,
    const int* __restrict__ Bw,
    const float* __restrict__ scale_p,
    const float* __restrict__ bias,
    float* __restrict__ C,
    int M, int N, int K)
{
    __shared__ unsigned short As[BM * BK];
    __shared__ unsigned short Bs[BN * BK];
    const int t = threadIdx.x, lane = t & 63, w = t >> 6;
    const int wm = w >> 1, wn = w & 1;
    int nwg = gridDim.x, bid = blockIdx.x;
    int swz = (nwg % 8 == 0) ? ((bid & 7) * (nwg >> 3) + (bid >> 3)) : bid;
    const int ntn = N / BN;
    const int row0 = (swz / ntn) * BM, col0 = (swz % ntn) * BN;
    f32x4 acc[4][4] = {};
    const int lr = lane & 15, lkbase = (lane >> 4) * 8;

    for (int kt = 0; kt < K; kt += BK) {
#pragma unroll
        for (int i = 0; i < 8; ++i) {
            const int r = i * 16 + (t >> 4), c = (t & 15) * 4;
            f32x4v v = *(const f32x4v*)&A[(size_t)(row0 + r) * K + kt + c];
            u16x4 o; o[0] = f2bf(v[0]); o[1] = f2bf(v[1]); o[2] = f2bf(v[2]); o[3] = f2bf(v[3]);
            *(u16x4*)&As[r * BK + c] = o;
        }
#pragma unroll
        for (int i = 0; i < 8; ++i) {
            const int r = i * 16 + (t >> 4), c = (t & 15) * 4;
            i32x4 v = *(const i32x4*)&Bw[(size_t)(col0 + r) * K + kt + c];
            u16x4 o; o[0] = f2bf((float)v[0]); o[1] = f2bf((float)v[1]);
                     o[2] = f2bf((float)v[2]); o[3] = f2bf((float)v[3]);
            *(u16x4*)&Bs[r * BK + c] = o;
        }
        __syncthreads();
#pragma unroll
        for (int ks = 0; ks < 2; ++ks) {
            const int lk = lkbase + ks * 8 * 4;
            bf16x8 af[4], bfr[4];
#pragma unroll
            for (int m = 0; m < 4; ++m) af[m] = *(const bf16x8*)&As[(wm * 64 + m * 16 + lr) * BK + lkbase + ks * 32];
#pragma unroll
            for (int n = 0; n < 4; ++n) bfr[n] = *(const bf16x8*)&Bs[(wn * 64 + n * 16 + lr) * BK + lkbase + ks * 32];
#pragma unroll
            for (int m = 0; m < 4; ++m)
#pragma unroll
                for (int n = 0; n < 4; ++n)
                    acc[m][n] = __builtin_amdgcn_mfma_f32_16x16x32_bf16(af[m], bfr[n], acc[m][n], 0, 0, 0);
            (void)lk;
        }
        __syncthreads();
    }
    const float s = scale_p[0];
    const int lq4 = (lane >> 4) * 4;
#pragma unroll
    for (int m = 0; m < 4; ++m)
#pragma unroll
        for (int n = 0; n < 4; ++n) {
            const int col = col0 + wn * 64 + n * 16 + lr;
            const float bv = bias[col];
#pragma unroll
            for (int j = 0; j < 4; ++j) {
                const int row = row0 + wm * 64 + m * 16 + lq4 + j;
                C[(size_t)row * N + col] = acc[m][n][j] * s + bv;
            }
        }
}

extern "C" void kernel_launch(void* const* d_in, const int* in_sizes, int n_in,
                              void* d_out, int out_size, void* d_ws, size_t ws_size,
                              hipStream_t stream) {
    const float* x     = (const float*)d_in[0];
    const int*   w8    = (const int*)d_in[1];
    const float* scale = (const float*)d_in[2];
    const float* bias  = (const float*)d_in[3];
    float* out = (float*)d_out;

    const int N = in_sizes[3];                    // 16384
    const int K = (int)((long)in_sizes[1] / N);   // 4096
    const int M = (int)((long)in_sizes[0] / K);   // 4096

    const size_t needA = (size_t)M * K;           // i8
    const size_t needB = (size_t)N * K;           // i8
    const size_t needS = (size_t)M * sizeof(float);
    const int NT = K / BKQ;

    const bool okShape = (M % BM8 == 0) && (N % BN8 == 0) && (K % BKQ == 0) &&
                         (K % 1024 == 0) && (K / 1024 <= 8) &&
                         (NT >= 4) && ((NT & 1) == 0);

    if (okShape && ws_size >= needA + needB + needS) {
        signed char* Aq = (signed char*)d_ws;
        signed char* Bq = Aq + needA;
        float*       sx = (float*)(Bq + needB);
        cvt_x_q8<<<M, 256, 0, stream>>>(x, Aq, sx, K);
        cvt_w_q8<<<4096, 256, 0, stream>>>(w8, Bq, (int)((size_t)N * K / 4));
        const int nblocks = (M / BM8) * (N / BN8);
        gemm8p_i8<<<nblocks, 512, 0, stream>>>(Aq, Bq, sx, scale, bias, out, M, N, K);
    } else {
        const int nblocks = (M / BM) * (N / BN);
        gemm_fused<<<nblocks, 256, 0, stream>>>(x, w8, scale, bias, out, M, N, K);
    }
}